// Round 1
// baseline (223.570 us; speedup 1.0000x reference)
//
#include <hip/hip_runtime.h>
#include <stdint.h>

namespace {
constexpr int kB = 65536;
constexpr int kT = 50;
constexpr int kM = 5;
constexpr int kRowF = kM * kT * 2 + kM;  // 505 floats per path_pred row
constexpr int kGtF  = kT * 2;            // 100 floats per path_gt row
constexpr int kBlocks = (kB * 8) / 256;  // 2048, octet-per-row exact cover

// ---- compile-time Threefry-2x32-20 (JAX PRNG) for the key split ----
constexpr uint32_t rotl_c(uint32_t v, int r) { return (v << r) | (v >> (32 - r)); }
constexpr uint64_t tf_c(uint32_t k0, uint32_t k1, uint32_t x0, uint32_t x1) {
  uint32_t ks2 = k0 ^ k1 ^ 0x1BD11BDAu;
  x0 += k0; x1 += k1;
  const int r0[4] = {13, 15, 26, 6};
  const int r1[4] = {17, 29, 16, 24};
  for (int i = 0; i < 4; i++) { x0 += x1; x1 = rotl_c(x1, r0[i]); x1 ^= x0; }
  x0 += k1; x1 += ks2 + 1u;
  for (int i = 0; i < 4; i++) { x0 += x1; x1 = rotl_c(x1, r1[i]); x1 ^= x0; }
  x0 += ks2; x1 += k0 + 2u;
  for (int i = 0; i < 4; i++) { x0 += x1; x1 = rotl_c(x1, r0[i]); x1 ^= x0; }
  x0 += k0; x1 += k1 + 3u;
  for (int i = 0; i < 4; i++) { x0 += x1; x1 = rotl_c(x1, r1[i]); x1 ^= x0; }
  x0 += k1; x1 += ks2 + 4u;
  for (int i = 0; i < 4; i++) { x0 += x1; x1 = rotl_c(x1, r0[i]); x1 ^= x0; }
  x0 += ks2; x1 += k0 + 5u;
  return ((uint64_t)x1 << 32) | x0;
}
// jax.random.key(42) -> key data (0,42). split(key,2): counts=[0,1,2,3],
// pairs (0,2) and (1,3). k1 = (h02.v0, h13.v0), k2 = (h02.v1, h13.v1).
constexpr uint64_t kS02 = tf_c(0u, 42u, 0u, 2u);
constexpr uint64_t kS13 = tf_c(0u, 42u, 1u, 3u);
constexpr uint32_t kK1A = (uint32_t)(kS02 & 0xFFFFFFFFu);
constexpr uint32_t kK1B = (uint32_t)(kS13 & 0xFFFFFFFFu);
constexpr uint32_t kK2A = (uint32_t)(kS02 >> 32);
constexpr uint32_t kK2B = (uint32_t)(kS13 >> 32);
}  // namespace

__device__ __forceinline__ uint32_t rotl32(uint32_t v, uint32_t r) {
  return (v << r) | (v >> (32u - r));
}

__device__ __forceinline__ void tf2x32(uint32_t k0, uint32_t k1, uint32_t x0,
                                       uint32_t x1, uint32_t& o0, uint32_t& o1) {
  uint32_t ks2 = k0 ^ k1 ^ 0x1BD11BDAu;
  x0 += k0; x1 += k1;
  const uint32_t r0[4] = {13u, 15u, 26u, 6u};
  const uint32_t r1[4] = {17u, 29u, 16u, 24u};
#pragma unroll
  for (int i = 0; i < 4; i++) { x0 += x1; x1 = rotl32(x1, r0[i]); x1 ^= x0; }
  x0 += k1; x1 += ks2 + 1u;
#pragma unroll
  for (int i = 0; i < 4; i++) { x0 += x1; x1 = rotl32(x1, r1[i]); x1 ^= x0; }
  x0 += ks2; x1 += k0 + 2u;
#pragma unroll
  for (int i = 0; i < 4; i++) { x0 += x1; x1 = rotl32(x1, r0[i]); x1 ^= x0; }
  x0 += k0; x1 += k1 + 3u;
#pragma unroll
  for (int i = 0; i < 4; i++) { x0 += x1; x1 = rotl32(x1, r1[i]); x1 ^= x0; }
  x0 += k1; x1 += ks2 + 4u;
#pragma unroll
  for (int i = 0; i < 4; i++) { x0 += x1; x1 = rotl32(x1, r0[i]); x1 ^= x0; }
  x0 += ks2; x1 += k0 + 5u;
  o0 = x0; o1 = x1;
}

__device__ __forceinline__ float huber1(float d) {
  float ad = fabsf(d);
  return ad < 1.0f ? 0.5f * d * d : ad - 0.5f;
}

// unaligned-16B load (traj rows are only 4B aligned: 505*4 = 2020 B stride)
__device__ __forceinline__ float4 loadu4(const float* p) {
  float4 v;
  __builtin_memcpy(&v, p, 16);
  return v;
}

// One octet (8 lanes) per row. 2048 blocks x 256 threads = 65536 rows exactly.
__global__ __launch_bounds__(256) void combo_kernel(
    const float* __restrict__ pp, const float* __restrict__ gt,
    const float* __restrict__ crp, const float* __restrict__ crg,
    float* __restrict__ partial) {
  const int tid = blockIdx.x * 256 + threadIdx.x;
  const int b = tid >> 3;
  const int sub = threadIdx.x & 7;

  const float* prow = pp + (size_t)b * kRowF;
  const float* grow = gt + (size_t)b * kGtF;

  // ---- stage path_gt row chunks (16B aligned: 400 B row stride) ----
  float gch[4][4];
#pragma unroll
  for (int i = 0; i < 4; i++) {
    int c = sub + 8 * i;
    if (c < 25) {
      float4 v = *reinterpret_cast<const float4*>(grow + 4 * c);
      gch[i][0] = v.x; gch[i][1] = v.y; gch[i][2] = v.z; gch[i][3] = v.w;
    } else {
      gch[i][0] = 0.f; gch[i][1] = 0.f; gch[i][2] = 0.f; gch[i][3] = 0.f;
    }
  }
  // gt last point (t=49) lives in chunk 24 (.z,.w) held by sub==0
  float glx = __shfl(gch[3][2], 0, 8);
  float gly = __shfl(gch[3][3], 0, 8);
  float refn = sqrtf(glx * glx + gly * gly);
  bool refnan = (glx != glx) || (gly != gly);

  float dist[kM], hub[kM];
  bool elig[kM];
  bool anyE = false;

#pragma unroll
  for (int m = 0; m < kM; m++) {
    const float* trow = prow + m * (kT * 2);
    float dsum = 0.f, hsum = 0.f;
    float tlx = 0.f, tly = 0.f;
#pragma unroll
    for (int i = 0; i < 4; i++) {
      int c = sub + 8 * i;
      if (c < 25) {
        float4 v = loadu4(trow + 4 * c);
        float dx0 = v.x - gch[i][0], dy0 = v.y - gch[i][1];
        float dx1 = v.z - gch[i][2], dy1 = v.w - gch[i][3];
        dsum += sqrtf(dx0 * dx0 + dy0 * dy0) + sqrtf(dx1 * dx1 + dy1 * dy1);
        hsum += huber1(dx0) + huber1(dy0) + huber1(dx1) + huber1(dy1);
        if (c == 24) { tlx = v.z; tly = v.w; }  // traj last point (t=49)
      }
    }
    // octet reduce (3 butterfly steps within groups of 8)
#pragma unroll
    for (int off = 1; off < 8; off <<= 1) {
      dsum += __shfl_xor(dsum, off, 8);
      hsum += __shfl_xor(hsum, off, 8);
    }
    dist[m] = dsum / 50.0f;
    hub[m] = hsum / 100.0f;

    tlx = __shfl(tlx, 0, 8);
    tly = __shfl(tly, 0, 8);
    float tn = sqrtf(tlx * tlx + tly * tly);
    float np = refn * tn;
    float dot = glx * tlx + gly * tly;
    float ca = dot / ((np == 0.f) ? 1.f : np);
    ca = fminf(fmaxf(ca, -1.f), 1.f);
    float ang = 57.29577951308232f * acosf(ca);
    ang = (np == 0.f) ? 0.f : ang;
    if (refnan || (tlx != tlx) || (tly != tly)) ang = 180.0f - 1e-5f;
    elig[m] = (ang <= 5.0f);
    anyE |= elig[m];
  }

  // argmin over eligible (first-min tie break, matches jnp.argmin)
  int best = 0;
  float bv = __builtin_inff();
#pragma unroll
  for (int m = 0; m < kM; m++) {
    float v = elig[m] ? dist[m] : __builtin_inff();
    if (v < bv) { bv = v; best = m; }
  }
  if (!anyE) {
    // rand_modes = jax.random.randint(key(42), (B,), 0, 5)
    uint32_t c0 = (uint32_t)b & 32767u;
    uint32_t hi = (uint32_t)b >> 15;
    uint32_t u0, u1, v0, v1;
    tf2x32(kK1A, kK1B, c0, c0 + 32768u, u0, u1);
    tf2x32(kK2A, kK2B, c0, c0 + 32768u, v0, v1);
    uint32_t hb = hi ? u1 : u0;
    uint32_t lb = hi ? v1 : v0;
    best = (int)(((hb % 5u) + (lb % 5u)) % 5u);  // 2^16 % 5 == 1 -> multiplier 1
  }

  // select hub[best] / prob[best] with unrolled compare chains (no scratch)
  float reg = hub[0];
#pragma unroll
  for (int m = 1; m < kM; m++)
    if (best == m) reg = hub[m];

  float4 pv = loadu4(prow + 500);  // probs 0..3
  float p4 = prow[504];
  float mx = fmaxf(fmaxf(fmaxf(pv.x, pv.y), fmaxf(pv.z, pv.w)), p4);
  float s = expf(pv.x - mx) + expf(pv.y - mx) + expf(pv.z - mx) +
            expf(pv.w - mx) + expf(p4 - mx);
  float lse = mx + logf(s);
  float pb = pv.x;
  if (best == 1) pb = pv.y;
  if (best == 2) pb = pv.z;
  if (best == 3) pb = pv.w;
  if (best == 4) pb = p4;
  float ce = lse - pb;

  // BCE term for this row
  float pc = crp[b], yc = crg[b];
  float lp = fmaxf(logf(pc), -100.0f);
  float l1 = fmaxf(log1pf(-pc), -100.0f);
  float bce = -(yc * lp + (1.0f - yc) * l1);

  float rowterm = ce + reg + bce;

  // one contribution per row (sub==0), wave butterfly, then block partial
  float contrib = (sub == 0) ? rowterm : 0.0f;
#pragma unroll
  for (int off = 1; off < 64; off <<= 1) contrib += __shfl_xor(contrib, off);

  __shared__ float sw[4];
  const int wid = threadIdx.x >> 6;
  if ((threadIdx.x & 63) == 0) sw[wid] = contrib;
  __syncthreads();
  if (threadIdx.x == 0)
    partial[blockIdx.x] = sw[0] + sw[1] + sw[2] + sw[3];
}

__global__ __launch_bounds__(256) void reduce_kernel(
    const float* __restrict__ partial, float* __restrict__ out) {
  float s = 0.f;
  for (int i = threadIdx.x; i < kBlocks; i += 256) s += partial[i];
#pragma unroll
  for (int off = 1; off < 64; off <<= 1) s += __shfl_xor(s, off);
  __shared__ float sw[4];
  const int wid = threadIdx.x >> 6;
  if ((threadIdx.x & 63) == 0) sw[wid] = s;
  __syncthreads();
  if (threadIdx.x == 0)
    out[0] = (sw[0] + sw[1] + sw[2] + sw[3]) * (1.0f / 65536.0f);
}

extern "C" void kernel_launch(void* const* d_in, const int* in_sizes, int n_in,
                              void* d_out, int out_size, void* d_ws,
                              size_t ws_size, hipStream_t stream) {
  const float* pp  = (const float*)d_in[0];  // (B, 505)
  const float* gt  = (const float*)d_in[1];  // (B, 50, 2)
  const float* crp = (const float*)d_in[2];  // (B, 1)
  const float* crg = (const float*)d_in[3];  // (B, 1)
  // d_in[4] (log_vars) is unused by the reference output.
  float* partial = (float*)d_ws;  // kBlocks floats

  combo_kernel<<<kBlocks, 256, 0, stream>>>(pp, gt, crp, crg, partial);
  reduce_kernel<<<1, 256, 0, stream>>>(partial, (float*)d_out);
}

// Round 2
// 220.011 us; speedup vs baseline: 1.0162x; 1.0162x over previous
//
#include <hip/hip_runtime.h>
#include <stdint.h>

namespace {
constexpr int kB = 65536;
constexpr int kT = 50;
constexpr int kM = 5;
constexpr int kRowF = kM * kT * 2 + kM;  // 505 floats per path_pred row
constexpr int kGtF  = kT * 2;            // 100 floats per path_gt row
constexpr int kBlocks = (kB * 8) / 256;  // 2048, octet-per-row exact cover

// cos(5 degrees): angle <= 5  <=>  cos(angle) >= cos(5deg) (acos monotone)
constexpr float kCos5 = 0.99619469809174553f;

// ---- compile-time Threefry-2x32-20 (JAX PRNG) for the key split ----
constexpr uint32_t rotl_c(uint32_t v, int r) { return (v << r) | (v >> (32 - r)); }
constexpr uint64_t tf_c(uint32_t k0, uint32_t k1, uint32_t x0, uint32_t x1) {
  uint32_t ks2 = k0 ^ k1 ^ 0x1BD11BDAu;
  x0 += k0; x1 += k1;
  const int r0[4] = {13, 15, 26, 6};
  const int r1[4] = {17, 29, 16, 24};
  for (int i = 0; i < 4; i++) { x0 += x1; x1 = rotl_c(x1, r0[i]); x1 ^= x0; }
  x0 += k1; x1 += ks2 + 1u;
  for (int i = 0; i < 4; i++) { x0 += x1; x1 = rotl_c(x1, r1[i]); x1 ^= x0; }
  x0 += ks2; x1 += k0 + 2u;
  for (int i = 0; i < 4; i++) { x0 += x1; x1 = rotl_c(x1, r0[i]); x1 ^= x0; }
  x0 += k0; x1 += k1 + 3u;
  for (int i = 0; i < 4; i++) { x0 += x1; x1 = rotl_c(x1, r1[i]); x1 ^= x0; }
  x0 += k1; x1 += ks2 + 4u;
  for (int i = 0; i < 4; i++) { x0 += x1; x1 = rotl_c(x1, r0[i]); x1 ^= x0; }
  x0 += ks2; x1 += k0 + 5u;
  return ((uint64_t)x1 << 32) | x0;
}
// jax.random.key(42) -> (0,42). split: pairs (0,2),(1,3).
constexpr uint64_t kS02 = tf_c(0u, 42u, 0u, 2u);
constexpr uint64_t kS13 = tf_c(0u, 42u, 1u, 3u);
constexpr uint32_t kK1A = (uint32_t)(kS02 & 0xFFFFFFFFu);
constexpr uint32_t kK1B = (uint32_t)(kS13 & 0xFFFFFFFFu);
constexpr uint32_t kK2A = (uint32_t)(kS02 >> 32);
constexpr uint32_t kK2B = (uint32_t)(kS13 >> 32);
}  // namespace

__device__ __forceinline__ uint32_t rotl32(uint32_t v, uint32_t r) {
  return (v << r) | (v >> (32u - r));
}

__device__ __forceinline__ void tf2x32(uint32_t k0, uint32_t k1, uint32_t x0,
                                       uint32_t x1, uint32_t& o0, uint32_t& o1) {
  uint32_t ks2 = k0 ^ k1 ^ 0x1BD11BDAu;
  x0 += k0; x1 += k1;
  const uint32_t r0[4] = {13u, 15u, 26u, 6u};
  const uint32_t r1[4] = {17u, 29u, 16u, 24u};
#pragma unroll
  for (int i = 0; i < 4; i++) { x0 += x1; x1 = rotl32(x1, r0[i]); x1 ^= x0; }
  x0 += k1; x1 += ks2 + 1u;
#pragma unroll
  for (int i = 0; i < 4; i++) { x0 += x1; x1 = rotl32(x1, r1[i]); x1 ^= x0; }
  x0 += ks2; x1 += k0 + 2u;
#pragma unroll
  for (int i = 0; i < 4; i++) { x0 += x1; x1 = rotl32(x1, r0[i]); x1 ^= x0; }
  x0 += k0; x1 += k1 + 3u;
#pragma unroll
  for (int i = 0; i < 4; i++) { x0 += x1; x1 = rotl32(x1, r1[i]); x1 ^= x0; }
  x0 += k1; x1 += ks2 + 4u;
#pragma unroll
  for (int i = 0; i < 4; i++) { x0 += x1; x1 = rotl32(x1, r0[i]); x1 ^= x0; }
  x0 += ks2; x1 += k0 + 5u;
  o0 = x0; o1 = x1;
}

__device__ __forceinline__ float huber1(float d) {
  float ad = fabsf(d);
  return ad < 1.0f ? 0.5f * d * d : ad - 0.5f;
}

// unaligned-16B load (traj rows are only 4B aligned: 505*4 = 2020 B stride);
// clang emits `load <4 x float>, align 4` -> wide global load where HW allows
__device__ __forceinline__ float4 loadu4(const float* p) {
  float4 v;
  __builtin_memcpy(&v, p, 16);
  return v;
}

// load the 4 chunks (c = sub + 8i) of one mode's 100-float traj block
__device__ __forceinline__ void load_chunks(float4 v[4], const float* base, int sub) {
#pragma unroll
  for (int i = 0; i < 3; i++) v[i] = loadu4(base + 4 * (sub + 8 * i));
  if (sub == 0) {
    v[3] = loadu4(base + 96);
  } else {
    v[3] = make_float4(0.f, 0.f, 0.f, 0.f);
  }
}

// One octet (8 lanes) per row. 2048 blocks x 256 threads = 65536 rows exactly.
__global__ __launch_bounds__(256) void combo_kernel(
    const float* __restrict__ pp, const float* __restrict__ gt,
    const float* __restrict__ crp, const float* __restrict__ crg,
    float* __restrict__ partial) {
  const int tid = blockIdx.x * 256 + threadIdx.x;
  const int b = tid >> 3;
  const int sub = threadIdx.x & 7;

  const float* prow = pp + (size_t)b * kRowF;
  const float* grow = gt + (size_t)b * kGtF;

  // ---- path_gt chunks (16B aligned: 400 B row stride) ----
  float4 g[4];
#pragma unroll
  for (int i = 0; i < 3; i++)
    g[i] = *reinterpret_cast<const float4*>(grow + 4 * (sub + 8 * i));
  g[3] = (sub == 0) ? *reinterpret_cast<const float4*>(grow + 96)
                    : make_float4(0.f, 0.f, 0.f, 0.f);

  // probs (needed in epilogue) issued early too
  float4 pv = loadu4(prow + 500);
  float p4 = prow[504];
  float pc = crp[b], yc = crg[b];

  // gt last point (t=49): chunk 24 (.z,.w) held by sub==0
  float glx = __shfl(g[3].z, 0, 8);
  float gly = __shfl(g[3].w, 0, 8);
  float refn = sqrtf(glx * glx + gly * gly);
  bool refnan = (glx != glx) || (gly != gly);

  float dist[kM], hs[kM];
  bool elig[kM];
  bool anyE = false;

  // 1-deep software pipeline over modes: load m+1 before computing m
  float4 cur[4], nxt[4];
  load_chunks(cur, prow, sub);

#pragma unroll
  for (int m = 0; m < kM; m++) {
    if (m < kM - 1) load_chunks(nxt, prow + (m + 1) * (kT * 2), sub);

    float dsum = 0.f, hsum = 0.f;
#pragma unroll
    for (int i = 0; i < 4; i++) {
      if (i < 3 || sub == 0) {
        float4 v = cur[i];
        float dx0 = v.x - g[i].x, dy0 = v.y - g[i].y;
        float dx1 = v.z - g[i].z, dy1 = v.w - g[i].w;
        dsum += sqrtf(dx0 * dx0 + dy0 * dy0) + sqrtf(dx1 * dx1 + dy1 * dy1);
        hsum += huber1(dx0) + huber1(dy0) + huber1(dx1) + huber1(dy1);
      }
    }
    // octet reduce dist now; DEFER huber reduce (only best mode needed)
#pragma unroll
    for (int off = 1; off < 8; off <<= 1) dsum += __shfl_xor(dsum, off, 8);
    dist[m] = dsum * (1.0f / 50.0f);
    hs[m] = hsum;

    // traj last point (t=49) = cur[3].zw on sub==0
    float tlx = __shfl(cur[3].z, 0, 8);
    float tly = __shfl(cur[3].w, 0, 8);
    float tn = sqrtf(tlx * tlx + tly * tly);
    float np = refn * tn;
    bool tnan = refnan || (tlx != tlx) || (tly != tly);
    bool e;
    if (np == 0.f) {
      e = true;  // angle := 0
    } else {
      float ca = (glx * tlx + gly * tly) / np;
      ca = fminf(fmaxf(ca, -1.f), 1.f);
      e = (ca >= kCos5);  // degrees(acos(ca)) <= 5
    }
    if (tnan) e = false;  // nan_mask overrides everything
    elig[m] = e;
    anyE |= e;

#pragma unroll
    for (int i = 0; i < 4; i++) cur[i] = nxt[i];
  }

  // argmin over eligible (first-min tie break, matches jnp.argmin)
  int best = 0;
  float bv = __builtin_inff();
#pragma unroll
  for (int m = 0; m < kM; m++) {
    float v = elig[m] ? dist[m] : __builtin_inff();
    if (v < bv) { bv = v; best = m; }
  }
  if (!anyE) {
    // rand_modes = jax.random.randint(key(42), (B,), 0, 5)
    uint32_t c0 = (uint32_t)b & 32767u;
    uint32_t hi = (uint32_t)b >> 15;
    uint32_t u0, u1, v0, v1;
    tf2x32(kK1A, kK1B, c0, c0 + 32768u, u0, u1);
    tf2x32(kK2A, kK2B, c0, c0 + 32768u, v0, v1);
    uint32_t hb = hi ? u1 : u0;
    uint32_t lb = hi ? v1 : v0;
    best = (int)(((hb % 5u) + (lb % 5u)) % 5u);  // 2^16 % 5 == 1
  }

  // select per-lane huber partial of best mode, THEN octet-reduce (3 swizzles)
  float regp = hs[0];
#pragma unroll
  for (int m = 1; m < kM; m++)
    if (best == m) regp = hs[m];
#pragma unroll
  for (int off = 1; off < 8; off <<= 1) regp += __shfl_xor(regp, off, 8);
  float reg = regp * (1.0f / 100.0f);

  // log-softmax CE with native exp/log
  float mx = fmaxf(fmaxf(fmaxf(pv.x, pv.y), fmaxf(pv.z, pv.w)), p4);
  float s = __expf(pv.x - mx) + __expf(pv.y - mx) + __expf(pv.z - mx) +
            __expf(pv.w - mx) + __expf(p4 - mx);
  float lse = mx + __logf(s);
  float pb = pv.x;
  if (best == 1) pb = pv.y;
  if (best == 2) pb = pv.z;
  if (best == 3) pb = pv.w;
  if (best == 4) pb = p4;
  float ce = lse - pb;

  // BCE term for this row
  float lp = fmaxf(__logf(pc), -100.0f);
  float l1 = fmaxf(__logf(1.0f - pc), -100.0f);
  float bce = -(yc * lp + (1.0f - yc) * l1);

  float rowterm = ce + reg + bce;

  // one contribution per row (sub==0), wave butterfly, then block partial
  float contrib = (sub == 0) ? rowterm : 0.0f;
#pragma unroll
  for (int off = 1; off < 64; off <<= 1) contrib += __shfl_xor(contrib, off);

  __shared__ float sw[4];
  const int wid = threadIdx.x >> 6;
  if ((threadIdx.x & 63) == 0) sw[wid] = contrib;
  __syncthreads();
  if (threadIdx.x == 0)
    partial[blockIdx.x] = sw[0] + sw[1] + sw[2] + sw[3];
}

__global__ __launch_bounds__(256) void reduce_kernel(
    const float* __restrict__ partial, float* __restrict__ out) {
  float s = 0.f;
  for (int i = threadIdx.x; i < kBlocks; i += 256) s += partial[i];
#pragma unroll
  for (int off = 1; off < 64; off <<= 1) s += __shfl_xor(s, off);
  __shared__ float sw[4];
  const int wid = threadIdx.x >> 6;
  if ((threadIdx.x & 63) == 0) sw[wid] = s;
  __syncthreads();
  if (threadIdx.x == 0)
    out[0] = (sw[0] + sw[1] + sw[2] + sw[3]) * (1.0f / 65536.0f);
}

extern "C" void kernel_launch(void* const* d_in, const int* in_sizes, int n_in,
                              void* d_out, int out_size, void* d_ws,
                              size_t ws_size, hipStream_t stream) {
  const float* pp  = (const float*)d_in[0];  // (B, 505)
  const float* gt  = (const float*)d_in[1];  // (B, 50, 2)
  const float* crp = (const float*)d_in[2];  // (B, 1)
  const float* crg = (const float*)d_in[3];  // (B, 1)
  // d_in[4] (log_vars) is unused by the reference output.
  float* partial = (float*)d_ws;  // kBlocks floats

  combo_kernel<<<kBlocks, 256, 0, stream>>>(pp, gt, crp, crg, partial);
  reduce_kernel<<<1, 256, 0, stream>>>(partial, (float*)d_out);
}

// Round 3
// 219.068 us; speedup vs baseline: 1.0205x; 1.0043x over previous
//
#include <hip/hip_runtime.h>
#include <stdint.h>

namespace {
constexpr int kB = 65536;
constexpr int kT = 50;
constexpr int kM = 5;
constexpr int kRowF = kM * kT * 2 + kM;  // 505 floats per path_pred row
constexpr int kGtF  = kT * 2;            // 100 floats per path_gt row
constexpr int kBlocks = (kB * 8) / 256;  // 2048, octet-per-row exact cover

// cos(5 degrees): angle <= 5  <=>  cos(angle) >= cos(5deg) (acos monotone)
constexpr float kCos5 = 0.99619469809174553f;

// ---- compile-time Threefry-2x32-20 (JAX PRNG) for the key split ----
constexpr uint32_t rotl_c(uint32_t v, int r) { return (v << r) | (v >> (32 - r)); }
constexpr uint64_t tf_c(uint32_t k0, uint32_t k1, uint32_t x0, uint32_t x1) {
  uint32_t ks2 = k0 ^ k1 ^ 0x1BD11BDAu;
  x0 += k0; x1 += k1;
  const int r0[4] = {13, 15, 26, 6};
  const int r1[4] = {17, 29, 16, 24};
  for (int i = 0; i < 4; i++) { x0 += x1; x1 = rotl_c(x1, r0[i]); x1 ^= x0; }
  x0 += k1; x1 += ks2 + 1u;
  for (int i = 0; i < 4; i++) { x0 += x1; x1 = rotl_c(x1, r1[i]); x1 ^= x0; }
  x0 += ks2; x1 += k0 + 2u;
  for (int i = 0; i < 4; i++) { x0 += x1; x1 = rotl_c(x1, r0[i]); x1 ^= x0; }
  x0 += k0; x1 += k1 + 3u;
  for (int i = 0; i < 4; i++) { x0 += x1; x1 = rotl_c(x1, r1[i]); x1 ^= x0; }
  x0 += k1; x1 += ks2 + 4u;
  for (int i = 0; i < 4; i++) { x0 += x1; x1 = rotl_c(x1, r0[i]); x1 ^= x0; }
  x0 += ks2; x1 += k0 + 5u;
  return ((uint64_t)x1 << 32) | x0;
}
// jax.random.key(42) -> (0,42). split: pairs (0,2),(1,3).
constexpr uint64_t kS02 = tf_c(0u, 42u, 0u, 2u);
constexpr uint64_t kS13 = tf_c(0u, 42u, 1u, 3u);
constexpr uint32_t kK1A = (uint32_t)(kS02 & 0xFFFFFFFFu);
constexpr uint32_t kK1B = (uint32_t)(kS13 & 0xFFFFFFFFu);
constexpr uint32_t kK2A = (uint32_t)(kS02 >> 32);
constexpr uint32_t kK2B = (uint32_t)(kS13 >> 32);
}  // namespace

typedef float f32x4 __attribute__((ext_vector_type(4)));
// wrapper so a 4B-aligned 16B vector load is expressible (traj rows are
// 2020B-strided -> only dword aligned; global_load_dwordx4 needs only 4B)
struct __attribute__((packed, aligned(4))) V4w { f32x4 v; };

__device__ __forceinline__ f32x4 load_nt_u(const float* p) {
  return __builtin_nontemporal_load(&reinterpret_cast<const V4w*>(p)->v);
}
__device__ __forceinline__ f32x4 load_nt_a(const float* p) {
  return __builtin_nontemporal_load(reinterpret_cast<const f32x4*>(p));
}

__device__ __forceinline__ uint32_t rotl32(uint32_t v, uint32_t r) {
  return (v << r) | (v >> (32u - r));
}

__device__ __forceinline__ void tf2x32(uint32_t k0, uint32_t k1, uint32_t x0,
                                       uint32_t x1, uint32_t& o0, uint32_t& o1) {
  uint32_t ks2 = k0 ^ k1 ^ 0x1BD11BDAu;
  x0 += k0; x1 += k1;
  const uint32_t r0[4] = {13u, 15u, 26u, 6u};
  const uint32_t r1[4] = {17u, 29u, 16u, 24u};
#pragma unroll
  for (int i = 0; i < 4; i++) { x0 += x1; x1 = rotl32(x1, r0[i]); x1 ^= x0; }
  x0 += k1; x1 += ks2 + 1u;
#pragma unroll
  for (int i = 0; i < 4; i++) { x0 += x1; x1 = rotl32(x1, r1[i]); x1 ^= x0; }
  x0 += ks2; x1 += k0 + 2u;
#pragma unroll
  for (int i = 0; i < 4; i++) { x0 += x1; x1 = rotl32(x1, r0[i]); x1 ^= x0; }
  x0 += k0; x1 += k1 + 3u;
#pragma unroll
  for (int i = 0; i < 4; i++) { x0 += x1; x1 = rotl32(x1, r1[i]); x1 ^= x0; }
  x0 += k1; x1 += ks2 + 4u;
#pragma unroll
  for (int i = 0; i < 4; i++) { x0 += x1; x1 = rotl32(x1, r0[i]); x1 ^= x0; }
  x0 += ks2; x1 += k0 + 5u;
  o0 = x0; o1 = x1;
}

__device__ __forceinline__ float huber1(float d) {
  float ad = fabsf(d);
  return ad < 1.0f ? 0.5f * d * d : ad - 0.5f;
}

// One octet (8 lanes) per row. 2048 blocks x 256 threads = 65536 rows exactly.
__global__ __launch_bounds__(256) void combo_kernel(
    const float* __restrict__ pp, const float* __restrict__ gt,
    const float* __restrict__ crp, const float* __restrict__ crg,
    float* __restrict__ partial) {
  const int tid = blockIdx.x * 256 + threadIdx.x;
  const int b = tid >> 3;
  const int sub = threadIdx.x & 7;

  const float* prow = pp + (size_t)b * kRowF;
  const float* grow = gt + (size_t)b * kGtF;

  const f32x4 vzero = {0.f, 0.f, 0.f, 0.f};

  // ---- path_gt chunks (16B aligned: 400 B row stride), nontemporal ----
  f32x4 g[4];
#pragma unroll
  for (int i = 0; i < 3; i++) g[i] = load_nt_a(grow + 4 * (sub + 8 * i));
  g[3] = (sub == 0) ? load_nt_a(grow + 96) : vzero;

  // epilogue-only inputs: load on sub==0 only (other lanes' values discarded)
  f32x4 pv = vzero;
  float p4 = 0.f, pc = 0.5f, yc = 0.5f;
  if (sub == 0) {
    pv = __builtin_nontemporal_load(&reinterpret_cast<const V4w*>(prow + 500)->v);
    p4 = prow[504];
    pc = crp[b];
    yc = crg[b];
  }

  // gt last point (t=49): chunk 24 (.z,.w) held by sub==0
  float glx = __shfl(g[3].z, 0, 8);
  float gly = __shfl(g[3].w, 0, 8);
  float refn = sqrtf(glx * glx + gly * gly);
  bool refnan = (glx != glx) || (gly != gly);

  float dist[kM], hs[kM];
  bool elig[kM];
  bool anyE = false;

#pragma unroll
  for (int m = 0; m < kM; m++) {
    const float* trow = prow + m * (kT * 2);
    f32x4 c0 = load_nt_u(trow + 4 * sub);
    f32x4 c1 = load_nt_u(trow + 4 * (sub + 8));
    f32x4 c2 = load_nt_u(trow + 4 * (sub + 16));
    f32x4 c3 = (sub == 0) ? load_nt_u(trow + 96) : vzero;

    float dsum = 0.f, hsum = 0.f;
    const f32x4 cc[4] = {c0, c1, c2, c3};
#pragma unroll
    for (int i = 0; i < 4; i++) {
      if (i < 3 || sub == 0) {
        f32x4 v = cc[i];
        float dx0 = v.x - g[i].x, dy0 = v.y - g[i].y;
        float dx1 = v.z - g[i].z, dy1 = v.w - g[i].w;
        dsum += sqrtf(dx0 * dx0 + dy0 * dy0) + sqrtf(dx1 * dx1 + dy1 * dy1);
        hsum += huber1(dx0) + huber1(dy0) + huber1(dx1) + huber1(dy1);
      }
    }
    // octet reduce dist now; DEFER huber reduce (only best mode needed)
#pragma unroll
    for (int off = 1; off < 8; off <<= 1) dsum += __shfl_xor(dsum, off, 8);
    dist[m] = dsum * (1.0f / 50.0f);
    hs[m] = hsum;

    // traj last point (t=49) = c3.zw on sub==0
    float tlx = __shfl(c3.z, 0, 8);
    float tly = __shfl(c3.w, 0, 8);
    float tn = sqrtf(tlx * tlx + tly * tly);
    float np = refn * tn;
    bool tnan = refnan || (tlx != tlx) || (tly != tly);
    bool e;
    if (np == 0.f) {
      e = true;  // angle := 0
    } else {
      float ca = (glx * tlx + gly * tly) / np;
      ca = fminf(fmaxf(ca, -1.f), 1.f);
      e = (ca >= kCos5);  // degrees(acos(ca)) <= 5
    }
    if (tnan) e = false;  // nan_mask overrides everything
    elig[m] = e;
    anyE |= e;
  }

  // argmin over eligible (first-min tie break, matches jnp.argmin)
  int best = 0;
  float bv = __builtin_inff();
#pragma unroll
  for (int m = 0; m < kM; m++) {
    float v = elig[m] ? dist[m] : __builtin_inff();
    if (v < bv) { bv = v; best = m; }
  }
  if (!anyE) {
    // rand_modes = jax.random.randint(key(42), (B,), 0, 5)
    uint32_t c0 = (uint32_t)b & 32767u;
    uint32_t hi = (uint32_t)b >> 15;
    uint32_t u0, u1, v0, v1;
    tf2x32(kK1A, kK1B, c0, c0 + 32768u, u0, u1);
    tf2x32(kK2A, kK2B, c0, c0 + 32768u, v0, v1);
    uint32_t hb = hi ? u1 : u0;
    uint32_t lb = hi ? v1 : v0;
    best = (int)(((hb % 5u) + (lb % 5u)) % 5u);  // 2^16 % 5 == 1
  }

  // select per-lane huber partial of best mode, THEN octet-reduce (3 swizzles)
  float regp = hs[0];
#pragma unroll
  for (int m = 1; m < kM; m++)
    if (best == m) regp = hs[m];
#pragma unroll
  for (int off = 1; off < 8; off <<= 1) regp += __shfl_xor(regp, off, 8);
  float reg = regp * (1.0f / 100.0f);

  // log-softmax CE with native exp/log (valid only on sub==0; discarded else)
  float mx = fmaxf(fmaxf(fmaxf(pv.x, pv.y), fmaxf(pv.z, pv.w)), p4);
  float s = __expf(pv.x - mx) + __expf(pv.y - mx) + __expf(pv.z - mx) +
            __expf(pv.w - mx) + __expf(p4 - mx);
  float lse = mx + __logf(s);
  float pb = pv.x;
  if (best == 1) pb = pv.y;
  if (best == 2) pb = pv.z;
  if (best == 3) pb = pv.w;
  if (best == 4) pb = p4;
  float ce = lse - pb;

  // BCE term for this row
  float lp = fmaxf(__logf(pc), -100.0f);
  float l1 = fmaxf(__logf(1.0f - pc), -100.0f);
  float bce = -(yc * lp + (1.0f - yc) * l1);

  float rowterm = ce + reg + bce;

  // one contribution per row (sub==0), wave butterfly, then block partial
  float contrib = (sub == 0) ? rowterm : 0.0f;
#pragma unroll
  for (int off = 1; off < 64; off <<= 1) contrib += __shfl_xor(contrib, off);

  __shared__ float sw[4];
  const int wid = threadIdx.x >> 6;
  if ((threadIdx.x & 63) == 0) sw[wid] = contrib;
  __syncthreads();
  if (threadIdx.x == 0)
    partial[blockIdx.x] = sw[0] + sw[1] + sw[2] + sw[3];
}

__global__ __launch_bounds__(256) void reduce_kernel(
    const float* __restrict__ partial, float* __restrict__ out) {
  float s = 0.f;
  for (int i = threadIdx.x; i < kBlocks; i += 256) s += partial[i];
#pragma unroll
  for (int off = 1; off < 64; off <<= 1) s += __shfl_xor(s, off);
  __shared__ float sw[4];
  const int wid = threadIdx.x >> 6;
  if ((threadIdx.x & 63) == 0) sw[wid] = s;
  __syncthreads();
  if (threadIdx.x == 0)
    out[0] = (sw[0] + sw[1] + sw[2] + sw[3]) * (1.0f / 65536.0f);
}

extern "C" void kernel_launch(void* const* d_in, const int* in_sizes, int n_in,
                              void* d_out, int out_size, void* d_ws,
                              size_t ws_size, hipStream_t stream) {
  const float* pp  = (const float*)d_in[0];  // (B, 505)
  const float* gt  = (const float*)d_in[1];  // (B, 50, 2)
  const float* crp = (const float*)d_in[2];  // (B, 1)
  const float* crg = (const float*)d_in[3];  // (B, 1)
  // d_in[4] (log_vars) is unused by the reference output.
  float* partial = (float*)d_ws;  // kBlocks floats

  combo_kernel<<<kBlocks, 256, 0, stream>>>(pp, gt, crp, crg, partial);
  reduce_kernel<<<1, 256, 0, stream>>>(partial, (float*)d_out);
}